// Round 9
// baseline (910.833 us; speedup 1.0000x reference)
//
#include <hip/hip_runtime.h>
#include <stdint.h>
#include <stddef.h>

// S=8192, D=1024 causal attention + QKV proj.
// Round-9: Br=64 intensity attack, register-feasible variant.
// attn: Br=64 x Bc=128, 8 waves (512 thr, launch_bounds(512,2): 256 unified
// regs = 128 arch + 128 AGPR). Wave c=0..7: QK^T 16-key slice (sacc[4],
// single depth-4 K ring); PV d-slice c*128..+128 x 64 rows (o_acc[4][8] =
// 128 AGPR). Bc=128 makes the P tile 16KB -> fits in LDS next to the 128KB
// Q tile, so NO P-holding through phase C (that trick is what pushed round
// 7/8 arch live to ~160 and spilled 520MB). Per-phase arch live <= ~110.
// K/V bytes per FLOP halved vs Br=32 (64 FLOP/B). 2 barriers per unit.
// Grid 256 = 64 p-pairs (light+heavy in-kernel halves) x key-parity-2,
// XCD-aligned windows. Merge combines 2 partials.

#define SEQ   8192
#define DIM   1024
#define MB    (1024 * 1024)

typedef __bf16 bf16x8 __attribute__((ext_vector_type(8)));
typedef float  f32x4  __attribute__((ext_vector_type(4)));

#define MFMA16(a, b, c) __builtin_amdgcn_mfma_f32_16x16x32_bf16((a), (b), (c), 0, 0, 0)

__device__ __forceinline__ uint16_t f2bf(float f) {
  uint32_t u = __builtin_bit_cast(uint32_t, f);
  return (uint16_t)((u + 0x7fffu + ((u >> 16) & 1u)) >> 16);
}
__device__ __forceinline__ float bf2f(uint16_t h) {
  uint32_t u = ((uint32_t)h) << 16;
  return __builtin_bit_cast(float, u);
}

typedef const __attribute__((address_space(1))) uint32_t* gas_t;
typedef __attribute__((address_space(3))) uint32_t* las_t;
__device__ __forceinline__ void async16(const void* g, void* l) {
  __builtin_amdgcn_global_load_lds((gas_t)g, (las_t)l, 16, 0, 0);
}

// ------------------------------------------------------- fused cast kernel
__global__ __launch_bounds__(256) void cast_all(const float* __restrict__ x,
                                                const float* __restrict__ wq,
                                                const float* __restrict__ wk,
                                                const float* __restrict__ wv,
                                                uint16_t* __restrict__ xb,
                                                uint16_t* __restrict__ wcat) {
  int b = blockIdx.x;
  const float* src;
  uint16_t* dst;
  int i;
  if (b < 8192) {
    src = x; dst = xb; i = (b * 256 + threadIdx.x) * 4;
  } else {
    int wb = b - 8192;
    int sel = wb >> 10;
    src = sel == 0 ? wq : (sel == 1 ? wk : wv);
    dst = wcat + sel * 1048576;
    i = ((wb & 1023) * 256 + threadIdx.x) * 4;
  }
  float4 v = *(const float4*)(src + i);
  ushort4 o;
  o.x = f2bf(v.x); o.y = f2bf(v.y); o.z = f2bf(v.z); o.w = f2bf(v.w);
  *(ushort4*)(dst + i) = o;
}

// ------------------------------------------------------------- QKV GEMM
__global__ __launch_bounds__(256) void qkv_gemm(const uint16_t* __restrict__ A,
                                                const uint16_t* __restrict__ B,
                                                uint16_t* __restrict__ Qblk,
                                                uint16_t* __restrict__ Kblk,
                                                uint16_t* __restrict__ Vblk) {
  __shared__ __align__(16) uint16_t As[128 * 64];
  __shared__ __align__(16) uint16_t Bs[128 * 64];
  const int t    = threadIdx.x;
  const int w    = t >> 6;
  const int lane = t & 63;
  const int lm   = lane & 15;
  const int qd   = lane >> 4;
  const int wrow = (w >> 1) * 64;
  const int wcol = (w & 1) * 64;
  const int rowbase = blockIdx.y * 128;
  const int colbase = blockIdx.x * 128;

  const int lrow = lane >> 3;
  const int lgrp = (lane & 7) ^ (lrow & 7);

  f32x4 acc[4][4] = {};

  for (int kb = 0; kb < DIM; kb += 64) {
    __syncthreads();
#pragma unroll
    for (int rep = 0; rep < 4; ++rep) {
      int r0 = rep * 32 + w * 8;
      async16(A + (size_t)(rowbase + r0 + lrow) * DIM + kb + lgrp * 8, As + r0 * 64);
      async16(B + (size_t)(colbase + r0 + lrow) * DIM + kb + lgrp * 8, Bs + r0 * 64);
    }
    __syncthreads();
#pragma unroll
    for (int kc = 0; kc < 2; ++kc) {
      bf16x8 af[4], bfr[4];
#pragma unroll
      for (int mt = 0; mt < 4; ++mt) {
        int r = wrow + mt * 16 + lm;
        af[mt] = *(const bf16x8*)(As + r * 64 + (((kc * 4 + qd) ^ (lm & 7)) * 8));
      }
#pragma unroll
      for (int nt = 0; nt < 4; ++nt) {
        int r = wcol + nt * 16 + lm;
        bfr[nt] = *(const bf16x8*)(Bs + r * 64 + (((kc * 4 + qd) ^ (lm & 7)) * 8));
      }
#pragma unroll
      for (int mt = 0; mt < 4; ++mt)
#pragma unroll
        for (int nt = 0; nt < 4; ++nt)
          acc[mt][nt] = MFMA16(af[mt], bfr[nt], acc[mt][nt]);
    }
  }

#pragma unroll
  for (int mt = 0; mt < 4; ++mt)
#pragma unroll
    for (int nt = 0; nt < 4; ++nt)
#pragma unroll
      for (int r = 0; r < 4; ++r) {
        int m = rowbase + wrow + mt * 16 + qd * 4 + r;
        int n = colbase + wcol + nt * 16 + lm;
        uint16_t v = f2bf(acc[mt][nt][r]);
        int nn = n & 1023;
        if (n < 2048) {
          // Q/K A-frag layout: row=m, feat=nn
          size_t off = (((size_t)(m >> 4) * 32 + (nn >> 5)) * 64 +
                        ((nn >> 3) & 3) * 16 + (m & 15)) * 8 + (nn & 7);
          if (n < 1024) Qblk[off] = v; else Kblk[off] = v;
        } else {
          // V B-frag layout: key=m, d=nn
          size_t off = (((size_t)(nn >> 4) * 256 + (m >> 5)) * 64 +
                        ((m >> 3) & 3) * 16 + (nn & 15)) * 8 + (m & 7);
          Vblk[off] = v;
        }
      }
}

// ------------------------------------------------------------ flash attention
// Br=64, Bc=128, 8 waves (512 thr), grid=256.
// b: xcd=b&7, s=b>>3 (0..31); par=s&1, p=xcd*8+(s>>1) (0..63).
// halves: tt = p then 127-p; jn = (tt>>1)+1; jg = par, par+2, ...
// wave c: QK^T keys c*16..+16 (sacc[4], depth-4 K ring, next-unit ring primed
// during phase C); PV d-slice c*128..+128 (o_acc[4][8]). Full 16KB Pb per
// unit (no P-holding in regs). V depth-4 ring primed during softmax.
__global__ __launch_bounds__(512, 2) void attn_kernel(const uint16_t* __restrict__ Qblk,
                                                      const uint16_t* __restrict__ Kblk,
                                                      const uint16_t* __restrict__ Vblk,
                                                      uint16_t* __restrict__ Pq,
                                                      float* __restrict__ Mm,
                                                      float* __restrict__ Ll) {
  __shared__ __align__(16) uint16_t Qs[65536];   // 128KB blocked Q tile (64 rows)
  __shared__ __align__(16) uint16_t Pb[8192];    // 16KB P tile (64 rows x 128 keys)
  __shared__ float stats[512];                   // [64][8]
  __shared__ float mrow[64];

  const int t    = threadIdx.x;
  const int w    = t >> 6;         // 0..7
  const int lane = t & 63;
  const int lm   = lane & 15;
  const int qd   = lane >> 4;
  const int c    = w;              // key/d slice
  const int b    = blockIdx.x;
  const int s    = b >> 3;
  const int par  = s & 1;
  const int p    = (b & 7) * 8 + (s >> 1);   // 0..63
  const float c1 = 0.045084220027780106f;    // log2(e)/sqrt(1024)

#pragma unroll 1
  for (int half = 0; half < 2; ++half) {
    const int tt   = half ? 127 - p : p;
    const int row0 = tt * 64;
    const int jn   = (tt >> 1) + 1;

    __syncthreads();  // previous half fully done (Qs reuse)
#pragma unroll
    for (int i = 0; i < 16; ++i)
      async16(Qblk + (size_t)tt * 65536 + ((w * 16 + i) * 64 + lane) * 8,
              Qs + (w * 16 + i) * 512);

    // prime K ring for jg=par (drained by barrier below)
    bf16x8 kr[4];
    {
      const uint16_t* kbp0 = Kblk + ((size_t)(par * 8 + c) * 32) * 512 + lane * 8;
#pragma unroll
      for (int i = 0; i < 4; ++i)
        kr[i] = *(const bf16x8*)(kbp0 + (size_t)i * 512);
    }
    __syncthreads();  // drain Qs DMA

    float m_run[4][4], l_run[4][4];
#pragma unroll
    for (int rf = 0; rf < 4; ++rf)
#pragma unroll
      for (int r = 0; r < 4; ++r) { m_run[rf][r] = -1e30f; l_run[rf][r] = 0.0f; }
    f32x4 o_acc[4][8] = {};

#pragma unroll 1
    for (int jg = par; jg < jn; jg += 2) {
      const uint16_t* kbp = Kblk + ((size_t)(jg * 8 + c) * 32) * 512 + lane * 8;
      const uint16_t* vbp = Vblk + ((size_t)(c * 8) * 256 + (size_t)jg * 4) * 512 + lane * 8;
      const uint16_t* qsp = Qs + lane * 8;

      // ---- Phase A: depth-4 K ring, 4 Q row-frags ------------------------
      f32x4 sacc[4] = {};
#pragma unroll
      for (int kb = 0; kb < 32; ++kb) {
        bf16x8 q0 = *(const bf16x8*)(qsp + (0 * 32 + kb) * 512);
        bf16x8 q1 = *(const bf16x8*)(qsp + (1 * 32 + kb) * 512);
        bf16x8 q2 = *(const bf16x8*)(qsp + (2 * 32 + kb) * 512);
        bf16x8 q3 = *(const bf16x8*)(qsp + (3 * 32 + kb) * 512);
        bf16x8 kcur = kr[kb & 3];
        if (kb < 28)
          kr[kb & 3] = *(const bf16x8*)(kbp + (size_t)(kb + 4) * 512);
        sacc[0] = MFMA16(q0, kcur, sacc[0]);
        sacc[1] = MFMA16(q1, kcur, sacc[1]);
        sacc[2] = MFMA16(q2, kcur, sacc[2]);
        sacc[3] = MFMA16(q3, kcur, sacc[3]);
      }

      // ---- causal mask (diagonal tile only) ------------------------------
      if (jg == jn - 1) {
#pragma unroll
        for (int rf = 0; rf < 4; ++rf)
#pragma unroll
          for (int r = 0; r < 4; ++r) {
            int col = jg * 128 + c * 16 + lm;
            int row = row0 + rf * 16 + qd * 4 + r;
            if (col > row) sacc[rf][r] = -1e30f;
          }
      }

      // ---- wave-local row max -> stats -----------------------------------
#pragma unroll
      for (int rf = 0; rf < 4; ++rf)
#pragma unroll
        for (int r = 0; r < 4; ++r) {
          float v = sacc[rf][r];
          v = fmaxf(v, __shfl_xor(v, 1));
          v = fmaxf(v, __shfl_xor(v, 2));
          v = fmaxf(v, __shfl_xor(v, 4));
          v = fmaxf(v, __shfl_xor(v, 8));
          if (lm == 0) stats[(rf * 16 + qd * 4 + r) * 8 + c] = v;
        }
      __syncthreads();  // (B1) stats ready; all waves past prior phase C

      // ---- global row max -> alpha; softmax; P -> Pb ---------------------
      float alpha[4][4], psum[4][4];
#pragma unroll
      for (int rf = 0; rf < 4; ++rf)
#pragma unroll
        for (int r = 0; r < 4; ++r) {
          int rl = rf * 16 + qd * 4 + r;
          float4 g0 = *(const float4*)&stats[rl * 8];
          float4 g1 = *(const float4*)&stats[rl * 8 + 4];
          float gm = fmaxf(fmaxf(fmaxf(g0.x, g0.y), fmaxf(g0.z, g0.w)),
                           fmaxf(fmaxf(g1.x, g1.y), fmaxf(g1.z, g1.w)));
          float mn = fmaxf(m_run[rf][r], gm);
          alpha[rf][r] = exp2f((m_run[rf][r] - mn) * c1);
          m_run[rf][r] = mn;
          psum[rf][r] = 0.0f;
        }
#pragma unroll
      for (int rf = 0; rf < 4; ++rf)
#pragma unroll
        for (int r = 0; r < 4; ++r) {
          float pv = exp2f((sacc[rf][r] - m_run[rf][r]) * c1);
          psum[rf][r] += pv;
          // key kk = c*16+lm: frag kc=c>>1, octet (c&1)*2+(lm>>3), e=lm&7
          Pb[((rf * 4 + (c >> 1)) * 64 + ((c & 1) * 2 + (lm >> 3)) * 16 +
              qd * 4 + r) * 8 + (lm & 7)] = f2bf(pv);
        }

      // ---- V ring prime (flies during psum reduce + rescale) -------------
      bf16x8 vr[4];
#pragma unroll
      for (int i = 0; i < 4; ++i)
        vr[i] = *(const bf16x8*)(vbp + (size_t)i * 256 * 512);

#pragma unroll
      for (int rf = 0; rf < 4; ++rf)
#pragma unroll
        for (int r = 0; r < 4; ++r) {
          float s2 = psum[rf][r];
          s2 += __shfl_xor(s2, 1);
          s2 += __shfl_xor(s2, 2);
          s2 += __shfl_xor(s2, 4);
          s2 += __shfl_xor(s2, 8);
          l_run[rf][r] = l_run[rf][r] * alpha[rf][r] + s2;
        }

      // ---- rescale O -----------------------------------------------------
#pragma unroll
      for (int rf = 0; rf < 4; ++rf)
#pragma unroll
        for (int dt = 0; dt < 8; ++dt)
#pragma unroll
          for (int r = 0; r < 4; ++r)
            o_acc[rf][dt][r] *= alpha[rf][r];

      __syncthreads();  // (B2) Pb ready

      // ---- next-unit K ring prime (lands during phase C) -----------------
      {
        const uint16_t* kbpn = Kblk + ((size_t)((jg + 2) * 8 + c) * 32) * 512 + lane * 8;
#pragma unroll
        for (int i = 0; i < 4; ++i)
          kr[i] = *(const bf16x8*)(kbpn + (size_t)i * 512);
      }

      // ---- Phase C: O += P @ V, depth-4 V ring ---------------------------
#pragma unroll
      for (int kc = 0; kc < 4; ++kc) {
        bf16x8 pf0 = *(const bf16x8*)(Pb + ((0 * 4 + kc) * 64 + lane) * 8);
        bf16x8 pf1 = *(const bf16x8*)(Pb + ((1 * 4 + kc) * 64 + lane) * 8);
        bf16x8 pf2 = *(const bf16x8*)(Pb + ((2 * 4 + kc) * 64 + lane) * 8);
        bf16x8 pf3 = *(const bf16x8*)(Pb + ((3 * 4 + kc) * 64 + lane) * 8);
#pragma unroll
        for (int dt = 0; dt < 8; ++dt) {
          int u = kc * 8 + dt;
          bf16x8 vf = vr[u & 3];
          if (u < 28) {
            int un = u + 4;
            vr[u & 3] = *(const bf16x8*)(vbp +
                ((size_t)(un & 7) * 256 + (un >> 3)) * 512);
          }
          o_acc[0][dt] = MFMA16(pf0, vf, o_acc[0][dt]);
          o_acc[1][dt] = MFMA16(pf1, vf, o_acc[1][dt]);
          o_acc[2][dt] = MFMA16(pf2, vf, o_acc[2][dt]);
          o_acc[3][dt] = MFMA16(pf3, vf, o_acc[3][dt]);
        }
      }
    }

    // ---- epilogue: l partials + unnormalized partial O -------------------
    __syncthreads();  // all waves past last stats read / Pb read
    if (lm == 0) {
#pragma unroll
      for (int rf = 0; rf < 4; ++rf)
#pragma unroll
        for (int r = 0; r < 4; ++r) {
          int rl = rf * 16 + qd * 4 + r;
          stats[rl * 8 + c] = l_run[rf][r];
          if (c == 0) mrow[rl] = m_run[rf][r];
        }
    }
    __syncthreads();
    if (t < 64) {
      float4 a0 = *(const float4*)&stats[t * 8];
      float4 a1 = *(const float4*)&stats[t * 8 + 4];
      Mm[par * SEQ + row0 + t] = mrow[t];
      Ll[par * SEQ + row0 + t] = (a0.x + a0.y + a0.z + a0.w) +
                                 (a1.x + a1.y + a1.z + a1.w);
    }
    uint16_t* Pp = Pq + (size_t)par * SEQ * DIM;
#pragma unroll
    for (int rf = 0; rf < 4; ++rf)
#pragma unroll
      for (int dt = 0; dt < 8; ++dt)
#pragma unroll
        for (int r = 0; r < 4; ++r) {
          int row = row0 + rf * 16 + qd * 4 + r;
          int d   = c * 128 + dt * 16 + lm;
          Pp[(size_t)row * DIM + d] = f2bf(o_acc[rf][dt][r]);
        }
  }
}

// ------------------------------------------------------------ merge partials
__global__ __launch_bounds__(256) void merge_kernel(const uint16_t* __restrict__ P0,
                                                    const uint16_t* __restrict__ P1,
                                                    const float* __restrict__ Mm,
                                                    const float* __restrict__ Ll,
                                                    float* __restrict__ out) {
  const int row = blockIdx.x;
  const int d0  = threadIdx.x * 4;
  const float c1 = 0.045084220027780106f;
  float m0 = Mm[row], m1 = Mm[SEQ + row];
  float l0 = Ll[row], l1 = Ll[SEQ + row];
  float m  = fmaxf(m0, m1);
  float a0 = exp2f((m0 - m) * c1);
  float a1 = exp2f((m1 - m) * c1);
  float inv = 1.0f / (a0 * l0 + a1 * l1);
  size_t off = (size_t)row * DIM + d0;
  ushort4 p0 = *(const ushort4*)(P0 + off);
  ushort4 p1 = *(const ushort4*)(P1 + off);
  float4 o;
  o.x = (a0 * bf2f(p0.x) + a1 * bf2f(p1.x)) * inv;
  o.y = (a0 * bf2f(p0.y) + a1 * bf2f(p1.y)) * inv;
  o.z = (a0 * bf2f(p0.z) + a1 * bf2f(p1.z)) * inv;
  o.w = (a0 * bf2f(p0.w) + a1 * bf2f(p1.w)) * inv;
  *(float4*)(out + off) = o;
}

// ---------------------------------------------------------------- launch
extern "C" void kernel_launch(void* const* d_in, const int* in_sizes, int n_in,
                              void* d_out, int out_size, void* d_ws, size_t ws_size,
                              hipStream_t stream) {
  (void)in_sizes; (void)n_in; (void)out_size; (void)ws_size;
  const float* x  = (const float*)d_in[0];
  const float* wq = (const float*)d_in[1];
  const float* wk = (const float*)d_in[2];
  const float* wv = (const float*)d_in[3];
  float* out = (float*)d_out;

  char* ws = (char*)d_ws;
  uint16_t* Qblk = (uint16_t*)(ws);                    // 16MB blocked
  uint16_t* Kblk = (uint16_t*)(ws + 16 * MB);          // 16MB blocked
  uint16_t* Vblk = (uint16_t*)(ws + 32 * MB);          // 16MB blocked
  uint16_t* P0   = (uint16_t*)(ws + 48 * MB);          // 16MB partial 0
  uint16_t* P1   = (uint16_t*)(ws + 64 * MB);          // 16MB partial 1
  uint16_t* xb   = (uint16_t*)(ws + 48 * MB);          // aliases P0 (dead after GEMM)
  uint16_t* wcat = (uint16_t*)(ws + 64 * MB);          // aliases P1 (dead after GEMM)
  float*    Mm   = (float*)(ws + 80 * MB);             // 2 x SEQ
  float*    Ll   = (float*)(ws + 80 * MB + 65536);     // 2 x SEQ

  cast_all<<<11264, 256, 0, stream>>>(x, wq, wk, wv, xb, wcat);
  qkv_gemm<<<dim3(24, 64), 256, 0, stream>>>(xb, wcat, Qblk, Kblk, Vblk);
  attn_kernel<<<256, 512, 0, stream>>>(Qblk, Kblk, Vblk, P0, Mm, Ll);
  merge_kernel<<<SEQ, 256, 0, stream>>>(P0, P1, Mm, Ll, out);
}

// Round 10
// 494.940 us; speedup vs baseline: 1.8403x; 1.8403x over previous
//
#include <hip/hip_runtime.h>
#include <stdint.h>
#include <stddef.h>

// S=8192, D=1024 causal attention + QKV proj.
// Round-10: attn reverted to the round-3 kernel verbatim (best measured:
// 346us). Only change: qkv_gemm epilogue no longer scatters 2B stores into
// the blocked layouts (64 stores/lane at 256B stride = 16-32x line-level
// write amplification). It now stages the 128x128 C-tile in LDS in the final
// blocked layout (reusing the 32KB As/Bs buffer) and copies out fully
// coalesced (8 x float4 per thread).

#define SEQ   8192
#define DIM   1024

typedef __bf16 bf16x8 __attribute__((ext_vector_type(8)));
typedef float  f32x4  __attribute__((ext_vector_type(4)));

#define MFMA16(a, b, c) __builtin_amdgcn_mfma_f32_16x16x32_bf16((a), (b), (c), 0, 0, 0)

__device__ __forceinline__ uint16_t f2bf(float f) {
  uint32_t u = __builtin_bit_cast(uint32_t, f);
  return (uint16_t)((u + 0x7fffu + ((u >> 16) & 1u)) >> 16);
}
__device__ __forceinline__ float bf2f(uint16_t h) {
  uint32_t u = ((uint32_t)h) << 16;
  return __builtin_bit_cast(float, u);
}

typedef const __attribute__((address_space(1))) uint32_t* gas_t;
typedef __attribute__((address_space(3))) uint32_t* las_t;
__device__ __forceinline__ void async16(const void* g, void* l) {
  __builtin_amdgcn_global_load_lds((gas_t)g, (las_t)l, 16, 0, 0);
}

// ------------------------------------------------------- fused cast kernel
__global__ __launch_bounds__(256) void cast_all(const float* __restrict__ x,
                                                const float* __restrict__ wq,
                                                const float* __restrict__ wk,
                                                const float* __restrict__ wv,
                                                uint16_t* __restrict__ xb,
                                                uint16_t* __restrict__ wcat) {
  int b = blockIdx.x;
  const float* src;
  uint16_t* dst;
  int i;
  if (b < 8192) {
    src = x; dst = xb; i = (b * 256 + threadIdx.x) * 4;
  } else {
    int wb = b - 8192;
    int sel = wb >> 10;
    src = sel == 0 ? wq : (sel == 1 ? wk : wv);
    dst = wcat + sel * 1048576;
    i = ((wb & 1023) * 256 + threadIdx.x) * 4;
  }
  float4 v = *(const float4*)(src + i);
  ushort4 o;
  o.x = f2bf(v.x); o.y = f2bf(v.y); o.z = f2bf(v.z); o.w = f2bf(v.w);
  *(ushort4*)(dst + i) = o;
}

// ------------------------------------------------------------- QKV GEMM
// async LDS staging (XOR-swizzled), 128x128 tile, BK=64.
// Epilogue: stage C-tile in LDS in blocked layout, coalesced copy-out.
__global__ __launch_bounds__(256) void qkv_gemm(const uint16_t* __restrict__ A,
                                                const uint16_t* __restrict__ B,
                                                uint16_t* __restrict__ Qblk,
                                                uint16_t* __restrict__ Kblk,
                                                uint16_t* __restrict__ Vblk) {
  __shared__ __align__(16) uint16_t Sh[16384];   // 32KB: As|Bs, then C staging
  uint16_t* As = Sh;            // 128*64
  uint16_t* Bs = Sh + 8192;     // 128*64
  const int t    = threadIdx.x;
  const int w    = t >> 6;
  const int lane = t & 63;
  const int lm   = lane & 15;
  const int qd   = lane >> 4;
  const int wrow = (w >> 1) * 64;
  const int wcol = (w & 1) * 64;
  const int rowbase = blockIdx.y * 128;
  const int colbase = blockIdx.x * 128;

  const int lrow = lane >> 3;
  const int lgrp = (lane & 7) ^ (lrow & 7);

  f32x4 acc[4][4] = {};

  for (int kb = 0; kb < DIM; kb += 64) {
    __syncthreads();
#pragma unroll
    for (int rep = 0; rep < 4; ++rep) {
      int r0 = rep * 32 + w * 8;
      async16(A + (size_t)(rowbase + r0 + lrow) * DIM + kb + lgrp * 8, As + r0 * 64);
      async16(B + (size_t)(colbase + r0 + lrow) * DIM + kb + lgrp * 8, Bs + r0 * 64);
    }
    __syncthreads();
#pragma unroll
    for (int kc = 0; kc < 2; ++kc) {
      bf16x8 af[4], bfr[4];
#pragma unroll
      for (int mt = 0; mt < 4; ++mt) {
        int r = wrow + mt * 16 + lm;
        af[mt] = *(const bf16x8*)(As + r * 64 + (((kc * 4 + qd) ^ (lm & 7)) * 8));
      }
#pragma unroll
      for (int nt = 0; nt < 4; ++nt) {
        int r = wcol + nt * 16 + lm;
        bfr[nt] = *(const bf16x8*)(Bs + r * 64 + (((kc * 4 + qd) ^ (lm & 7)) * 8));
      }
#pragma unroll
      for (int mt = 0; mt < 4; ++mt)
#pragma unroll
        for (int nt = 0; nt < 4; ++nt)
          acc[mt][nt] = MFMA16(af[mt], bfr[nt], acc[mt][nt]);
    }
  }

  // ---- epilogue: stage blocked-layout C tile in LDS ----------------------
  __syncthreads();  // all waves done reading As/Bs
#pragma unroll
  for (int mt = 0; mt < 4; ++mt)
#pragma unroll
    for (int nt = 0; nt < 4; ++nt)
#pragma unroll
      for (int r = 0; r < 4; ++r) {
        int ml = wrow + mt * 16 + qd * 4 + r;   // 0..127
        int nl = wcol + nt * 16 + lm;           // 0..127
        uint16_t v = f2bf(acc[mt][nt][r]);
        int off;
        if (colbase < 2048) {
          // Q/K A-frag: frag (ml>>4, nl>>5), elem ((nl>>3)&3,(ml&15),(nl&7))
          off = ((ml >> 4) * 4 + (nl >> 5)) * 512 + ((nl >> 3) & 3) * 128 +
                (ml & 15) * 8 + (nl & 7);
        } else {
          // V B-frag (d-major): frag (nl>>4, ml>>5), elem ((ml>>3)&3,(nl&15),(ml&7))
          off = ((nl >> 4) * 4 + (ml >> 5)) * 512 + ((ml >> 3) & 3) * 128 +
                (nl & 15) * 8 + (ml & 7);
        }
        Sh[off] = v;
      }
  __syncthreads();

  // ---- coalesced copy-out: 32 frags x 1KB = 32KB -------------------------
  {
    uint16_t* dst = colbase < 1024 ? Qblk : (colbase < 2048 ? Kblk : Vblk);
    const int cb = colbase & 1023;
#pragma unroll
    for (int i = 0; i < 8; ++i) {
      int ch  = i * 256 + t;      // 0..2047 16B-chunks
      int tf  = ch >> 6;          // tile-frag 0..31
      int idx = ch & 63;          // 16B chunk within frag
      size_t gbase;
      if (colbase < 2048)
        gbase = ((size_t)((rowbase >> 4) + (tf >> 2)) * 32 + (cb >> 5) + (tf & 3)) * 512;
      else
        gbase = ((size_t)((cb >> 4) + (tf >> 2)) * 256 + (rowbase >> 5) + (tf & 3)) * 512;
      *(float4*)(dst + gbase + idx * 8) = *(const float4*)(Sh + tf * 512 + idx * 8);
    }
  }
}

// ------------------------------------------------------------ flash attention
// Br=32 rows, Bc=256 keys/iter, 16 waves (1024 thr), grid=256.
// XCD-aligned mapping: xcd=b&7, slot=b>>3; p = xcd*16 + slot/2, par = slot&1.
// Per wave: QK^T 16-key slice (depth-4 K ring carried across phases), PV
// 64-wide d-slice (o_acc[2][4]); V kc=0,1 prefetched during softmax, depth-2
// ring in phase C; next-iter K chunk prefetched into the ring at phase C top.
__global__ __launch_bounds__(1024) void attn_kernel(const uint16_t* __restrict__ Qblk,
                                                    const uint16_t* __restrict__ Kblk,
                                                    const uint16_t* __restrict__ Vblk,
                                                    uint16_t* __restrict__ P0,
                                                    uint16_t* __restrict__ P1,
                                                    float* __restrict__ Mm,
                                                    float* __restrict__ Ll) {
  __shared__ __align__(16) uint16_t Qs[32768];   // 64KB blocked Q tile
  __shared__ __align__(16) uint16_t Pb[8192];    // 16KB P (A-frag blocked)
  __shared__ float stats[32][16];
  __shared__ float mrow[32];

  const int t    = threadIdx.x;
  const int w    = t >> 6;         // 0..15
  const int lane = t & 63;
  const int lm   = lane & 15;
  const int qd   = lane >> 4;
  const int slot = blockIdx.x >> 3;
  const int p    = (blockIdx.x & 7) * 16 + (slot >> 1);
  const int par  = slot & 1;
  const float c1 = 0.045084220027780106f;  // log2(e)/sqrt(1024)

#pragma unroll 1
  for (int half = 0; half < 2; ++half) {
    const int tt   = half ? 255 - p : p;
    const int row0 = tt * 32;
    const int jn   = (tt >> 3) + 1;

    __syncthreads();  // previous half done with Qs
#pragma unroll
    for (int i = 0; i < 4; ++i)
      async16(Qblk + ((size_t)(tt * 64 + w * 4 + i)) * 512 + lane * 8,
              Qs + (w * 4 + i) * 512);

    // prime K ring for jg=par (drained by the barrier below)
    bf16x8 kr[4];
    {
      const uint16_t* kbp0 = Kblk + ((size_t)(par * 16 + w) * 32) * 512 + lane * 8;
#pragma unroll
      for (int c = 0; c < 4; ++c)
        kr[c] = *(const bf16x8*)(kbp0 + (size_t)c * 512);
    }
    __syncthreads();  // drain Qs DMA

    float m_run[2][4], l_run[2][4];
#pragma unroll
    for (int mt = 0; mt < 2; ++mt)
#pragma unroll
      for (int r = 0; r < 4; ++r) { m_run[mt][r] = -1e30f; l_run[mt][r] = 0.0f; }
    f32x4 o_acc[2][4] = {};

#pragma unroll 1
    for (int jg = par; jg < jn; jg += 2) {
      const uint16_t* kbp = Kblk + ((size_t)(jg * 16 + w) * 32) * 512 + lane * 8;
      const uint16_t* vbp = Vblk + ((size_t)(w * 4) * 256 + jg * 8) * 512 + lane * 8;
      const uint16_t* qsp = Qs + lane * 8;

      // ---- Phase A: depth-4 rolling K ring (single 16-key stream) --------
      f32x4 sacc[2] = {};
#pragma unroll
      for (int kb = 0; kb < 32; ++kb) {
        bf16x8 q0 = *(const bf16x8*)(qsp + kb * 512);
        bf16x8 q1 = *(const bf16x8*)(qsp + (32 + kb) * 512);
        bf16x8 kcur = kr[kb & 3];
        if (kb < 28)
          kr[kb & 3] = *(const bf16x8*)(kbp + (size_t)(kb + 4) * 512);
        sacc[0] = MFMA16(q0, kcur, sacc[0]);
        sacc[1] = MFMA16(q1, kcur, sacc[1]);
      }

      // ---- causal mask (diagonal tile only) ------------------------------
      if (jg == jn - 1) {
#pragma unroll
        for (int mt = 0; mt < 2; ++mt)
#pragma unroll
          for (int r = 0; r < 4; ++r) {
            int col = jg * 256 + w * 16 + lm;
            int row = row0 + mt * 16 + qd * 4 + r;
            if (col > row) sacc[mt][r] = -1e30f;
          }
      }

      // ---- wave-local row max -> stats -----------------------------------
#pragma unroll
      for (int mt = 0; mt < 2; ++mt)
#pragma unroll
        for (int r = 0; r < 4; ++r) {
          float v = sacc[mt][r];
          v = fmaxf(v, __shfl_xor(v, 1));
          v = fmaxf(v, __shfl_xor(v, 2));
          v = fmaxf(v, __shfl_xor(v, 4));
          v = fmaxf(v, __shfl_xor(v, 8));
          if (lm == 0) stats[mt * 16 + qd * 4 + r][w] = v;
        }
      __syncthreads();  // (1) stats ready; also gates Pb reuse (all waves past
                        // prior phase C)

      // ---- V prefetch kc=0 (flies during softmax) ------------------------
      bf16x8 vr0[4], vr1[4];
#pragma unroll
      for (int dt = 0; dt < 4; ++dt)
        vr0[dt] = *(const bf16x8*)(vbp + ((size_t)dt * 256 + 0) * 512);

      // ---- softmax in registers; P (blocked) to LDS ----------------------
      float alpha[2][4], psum[2][4];
#pragma unroll
      for (int mt = 0; mt < 2; ++mt)
#pragma unroll
        for (int r = 0; r < 4; ++r) {
          int rl = mt * 16 + qd * 4 + r;
          float4 g0 = *(const float4*)&stats[rl][0];
          float4 g1 = *(const float4*)&stats[rl][4];
          float4 g2 = *(const float4*)&stats[rl][8];
          float4 g3 = *(const float4*)&stats[rl][12];
          float gm = fmaxf(
              fmaxf(fmaxf(fmaxf(g0.x, g0.y), fmaxf(g0.z, g0.w)),
                    fmaxf(fmaxf(g1.x, g1.y), fmaxf(g1.z, g1.w))),
              fmaxf(fmaxf(fmaxf(g2.x, g2.y), fmaxf(g2.z, g2.w)),
                    fmaxf(fmaxf(g3.x, g3.y), fmaxf(g3.z, g3.w))));
          float mn = fmaxf(m_run[mt][r], gm);
          alpha[mt][r] = exp2f((m_run[mt][r] - mn) * c1);
          m_run[mt][r] = mn;
          psum[mt][r] = 0.0f;
        }
#pragma unroll
      for (int mt = 0; mt < 2; ++mt)
#pragma unroll
        for (int r = 0; r < 4; ++r) {
          float pv = exp2f((sacc[mt][r] - m_run[mt][r]) * c1);
          psum[mt][r] += pv;
          // wave w owns keys w*16+lm: frag kt=w>>1, k8=(w&1)*2+(lm>>3), e=lm&7
          Pb[((mt * 8 + (w >> 1)) * 64 + ((w & 1) * 2 + (lm >> 3)) * 16 +
              qd * 4 + r) * 8 + (lm & 7)] = f2bf(pv);
        }

      // ---- V prefetch kc=1 ----------------------------------------------
#pragma unroll
      for (int dt = 0; dt < 4; ++dt)
        vr1[dt] = *(const bf16x8*)(vbp + ((size_t)dt * 256 + 1) * 512);

#pragma unroll
      for (int mt = 0; mt < 2; ++mt)
#pragma unroll
        for (int r = 0; r < 4; ++r) {
          float s2 = psum[mt][r];
          s2 += __shfl_xor(s2, 1);
          s2 += __shfl_xor(s2, 2);
          s2 += __shfl_xor(s2, 4);
          s2 += __shfl_xor(s2, 8);
          l_run[mt][r] = l_run[mt][r] * alpha[mt][r] + s2;
        }
      __syncthreads();  // (2) Pb ready

      // ---- next-iter K prefetch into ring (lands during phase C) ---------
      {
        const uint16_t* kbpn = Kblk + ((size_t)((jg + 2) * 16 + w) * 32) * 512 + lane * 8;
#pragma unroll
        for (int c = 0; c < 4; ++c)
          kr[c] = *(const bf16x8*)(kbpn + (size_t)c * 512);
      }

      // ---- rescale O -----------------------------------------------------
#pragma unroll
      for (int mt = 0; mt < 2; ++mt)
#pragma unroll
        for (int dt = 0; dt < 4; ++dt)
#pragma unroll
          for (int r = 0; r < 4; ++r)
            o_acc[mt][dt][r] *= alpha[mt][r];

      // ---- Phase C: O += P @ V, depth-2 V ring ---------------------------
#pragma unroll
      for (int kc = 0; kc < 8; ++kc) {
        bf16x8 pf0 = *(const bf16x8*)(Pb + (kc * 64 + lane) * 8);
        bf16x8 pf1 = *(const bf16x8*)(Pb + ((8 + kc) * 64 + lane) * 8);
#pragma unroll
        for (int dt = 0; dt < 4; ++dt) {
          bf16x8 vf = (kc & 1) ? vr1[dt] : vr0[dt];
          o_acc[0][dt] = MFMA16(pf0, vf, o_acc[0][dt]);
          o_acc[1][dt] = MFMA16(pf1, vf, o_acc[1][dt]);
        }
        if (kc < 6) {
#pragma unroll
          for (int dt = 0; dt < 4; ++dt) {
            if (kc & 1)
              vr1[dt] = *(const bf16x8*)(vbp + ((size_t)dt * 256 + kc + 2) * 512);
            else
              vr0[dt] = *(const bf16x8*)(vbp + ((size_t)dt * 256 + kc + 2) * 512);
          }
        }
      }
    }

    // ---- epilogue: stats (reused as lsum) + unnormalized partial O -------
    if (lm == 0) {
#pragma unroll
      for (int mt = 0; mt < 2; ++mt)
#pragma unroll
        for (int r = 0; r < 4; ++r) {
          int rl = mt * 16 + qd * 4 + r;
          stats[rl][w] = l_run[mt][r];
          if (w == 0) mrow[rl] = m_run[mt][r];
        }
    }
    __syncthreads();
    if (t < 32) {
      float4 a0 = *(const float4*)&stats[t][0];
      float4 a1 = *(const float4*)&stats[t][4];
      float4 a2 = *(const float4*)&stats[t][8];
      float4 a3 = *(const float4*)&stats[t][12];
      Mm[par * SEQ + row0 + t] = mrow[t];
      Ll[par * SEQ + row0 + t] = (a0.x + a0.y + a0.z + a0.w) +
                                 (a1.x + a1.y + a1.z + a1.w) +
                                 (a2.x + a2.y + a2.z + a2.w) +
                                 (a3.x + a3.y + a3.z + a3.w);
    }
    uint16_t* Pp = par ? P1 : P0;
#pragma unroll
    for (int mt = 0; mt < 2; ++mt)
#pragma unroll
      for (int dt = 0; dt < 4; ++dt)
#pragma unroll
        for (int r = 0; r < 4; ++r) {
          int row = row0 + mt * 16 + qd * 4 + r;
          int d   = w * 64 + dt * 16 + lm;
          Pp[(size_t)row * DIM + d] = f2bf(o_acc[mt][dt][r]);
        }
  }
}

// ------------------------------------------------------------ merge partials
__global__ __launch_bounds__(256) void merge_kernel(const uint16_t* __restrict__ P0,
                                                    const uint16_t* __restrict__ P1,
                                                    const float* __restrict__ Mm,
                                                    const float* __restrict__ Ll,
                                                    float* __restrict__ out) {
  const int row = blockIdx.x;
  const int d0  = threadIdx.x * 4;
  const float c1 = 0.045084220027780106f;
  float m0 = Mm[row], m1 = Mm[SEQ + row];
  float l0 = Ll[row], l1 = Ll[SEQ + row];
  float m  = fmaxf(m0, m1);
  float a0 = exp2f((m0 - m) * c1);
  float a1 = exp2f((m1 - m) * c1);
  float inv = 1.0f / (a0 * l0 + a1 * l1);
  ushort4 p0 = *(const ushort4*)(P0 + (size_t)row * DIM + d0);
  ushort4 p1 = *(const ushort4*)(P1 + (size_t)row * DIM + d0);
  float4 o;
  o.x = (a0 * bf2f(p0.x) + a1 * bf2f(p1.x)) * inv;
  o.y = (a0 * bf2f(p0.y) + a1 * bf2f(p1.y)) * inv;
  o.z = (a0 * bf2f(p0.z) + a1 * bf2f(p1.z)) * inv;
  o.w = (a0 * bf2f(p0.w) + a1 * bf2f(p1.w)) * inv;
  *(float4*)(out + (size_t)row * DIM + d0) = o;
}

// ---------------------------------------------------------------- launch
extern "C" void kernel_launch(void* const* d_in, const int* in_sizes, int n_in,
                              void* d_out, int out_size, void* d_ws, size_t ws_size,
                              hipStream_t stream) {
  (void)in_sizes; (void)n_in; (void)out_size; (void)ws_size;
  const float* x  = (const float*)d_in[0];
  const float* wq = (const float*)d_in[1];
  const float* wk = (const float*)d_in[2];
  const float* wv = (const float*)d_in[3];
  float* out = (float*)d_out;

  char* ws = (char*)d_ws;
  uint16_t* Qblk = (uint16_t*)(ws);                  // 16MB blocked
  uint16_t* Kblk = (uint16_t*)(ws + 16777216);       // 16MB blocked
  uint16_t* Vblk = (uint16_t*)(ws + 33554432);       // 16MB blocked
  uint16_t* P0   = (uint16_t*)(ws + 50331648);       // 16MB partial 0
  uint16_t* xb   = (uint16_t*)(ws + 67108864);       // 16MB
  uint16_t* P1   = (uint16_t*)(ws + 67108864);       // aliases xb (dead after GEMM)
  uint16_t* wcat = (uint16_t*)(ws + 83886080);       // 6MB
  float*    Mm   = (float*)(ws + 83886080);          // aliases wcat (dead after GEMM)
  float*    Ll   = (float*)(ws + 83886080 + 65536);

  cast_all<<<11264, 256, 0, stream>>>(x, wq, wk, wv, xb, wcat);
  qkv_gemm<<<dim3(24, 64), 256, 0, stream>>>(xb, wcat, Qblk, Kblk, Vblk);
  attn_kernel<<<256, 1024, 0, stream>>>(Qblk, Kblk, Vblk, P0, P1, Mm, Ll);
  merge_kernel<<<SEQ, 256, 0, stream>>>(P0, P1, Mm, Ll, out);
}